// Round 3
// baseline (194.272 us; speedup 1.0000x reference)
//
#include <hip/hip_runtime.h>
#include <math.h>

#define NXC 200   // grid edge
#define NBB 512   // batch
#define NQ  8     // row-groups per batch
#define NR  25    // rows per group
#define RST 68    // LDS row stride (16B-aligned, breaks pow2 banks)

// Workspace layout (float offsets)
#define WS_CSP 0                                   // [512][8][200] heat col-sum partials
#define WS_CLP (WS_CSP + NBB*NQ*NXC)               // [512][8][200] layout col-sum partials
#define WS_RS  (WS_CLP + NBB*NQ*NXC)               // [512][200] heat row sums
#define WS_RL  (WS_RS  + NBB*NXC)                  // [512][200] layout row sums
#define WS_BROW (WS_RL + NBB*NXC)                  // [512][4][200] heat rows 0,1,198,199
#define WS_BCOL (WS_BROW + NBB*4*NXC)              // [512][4][200] heat cols 0,1,198,199

// ---------------- Phase 1: streaming scan, no cross-lane ops in the loop ----
// Block g: batch b = g/8, row-group q = g%8 (rows 25q .. 25q+24).
// Wave w owns local rows rl = w + 4k. Lane l<50 loads float4 (cols 4l..4l+3).
// Column partials accumulate in registers; per-lane row partial goes to LDS.
__global__ __launch_bounds__(256, 1) void heat_phase1(
    const float* __restrict__ layout, const float* __restrict__ heat,
    float* __restrict__ ws) {
  const int g    = blockIdx.x;
  const int b    = g >> 3;
  const int q    = g & 7;
  const int R0   = NR * q;
  const int tid  = threadIdx.x;
  const int wave = tid >> 6;
  const int lane = tid & 63;

  __shared__ __align__(16) float s_hrow[NR][RST];
  __shared__ __align__(16) float s_lrow[NR][RST];
  __shared__ float s_hcol[4][NXC];
  __shared__ float s_lcol[4][NXC];
  __shared__ float s_bc[4][NR];    // boundary-col values for owned rows

  const float4* __restrict__ hp =
      reinterpret_cast<const float4*>(heat + (size_t)b * NXC * NXC);
  const float4* __restrict__ lp =
      reinterpret_cast<const float4*>(layout + (size_t)b * NXC * NXC);

  float hc0=0.f,hc1=0.f,hc2=0.f,hc3=0.f;
  float lc0=0.f,lc1=0.f,lc2=0.f,lc3=0.f;
  const bool act = (lane < 50);

  #pragma unroll
  for (int k = 0; k < 7; ++k) {
    const int rl = wave + 4 * k;               // wave-uniform
    if (rl < NR) {
      const int i = R0 + rl;                   // global row
      float4 hv = make_float4(0.f,0.f,0.f,0.f);
      float4 lv = make_float4(0.f,0.f,0.f,0.f);
      if (act) {
        hv = hp[i * 50 + lane];
        lv = lp[i * 50 + lane];
      }
      hc0 += hv.x; hc1 += hv.y; hc2 += hv.z; hc3 += hv.w;
      lc0 += lv.x; lc1 += lv.y; lc2 += lv.z; lc3 += lv.w;
      if (act) {
        s_hrow[rl][lane] = (hv.x + hv.y) + (hv.z + hv.w);
        s_lrow[rl][lane] = (lv.x + lv.y) + (lv.z + lv.w);
        // boundary rows of heat (i in {0,1,198,199}) -> ws, coalesced float4
        if (i <= 1 || i >= NXC - 2) {
          const int bi = (i <= 1) ? i : i - (NXC - 4);
          float4* dst = reinterpret_cast<float4*>(
              ws + WS_BROW + ((size_t)b * 4 + bi) * NXC);
          dst[lane] = hv;
        }
        // boundary cols of heat: j=0,1 from lane 0; j=198,199 from lane 49
        if (lane == 0)  { s_bc[0][rl] = hv.x; s_bc[1][rl] = hv.y; }
        if (lane == 49) { s_bc[2][rl] = hv.z; s_bc[3][rl] = hv.w; }
      }
    }
  }

  if (act) {
    s_hcol[wave][4*lane+0] = hc0; s_hcol[wave][4*lane+1] = hc1;
    s_hcol[wave][4*lane+2] = hc2; s_hcol[wave][4*lane+3] = hc3;
    s_lcol[wave][4*lane+0] = lc0; s_lcol[wave][4*lane+1] = lc1;
    s_lcol[wave][4*lane+2] = lc2; s_lcol[wave][4*lane+3] = lc3;
  }
  __syncthreads();

  // column-sum partials for this row-group -> ws (disjoint slots, no atomics)
  if (tid < NXC) {
    const float a = (s_hcol[0][tid] + s_hcol[1][tid]) + (s_hcol[2][tid] + s_hcol[3][tid]);
    const float c = (s_lcol[0][tid] + s_lcol[1][tid]) + (s_lcol[2][tid] + s_lcol[3][tid]);
    ws[WS_CSP + ((size_t)b * NQ + q) * NXC + tid] = a;
    ws[WS_CLP + ((size_t)b * NQ + q) * NXC + tid] = c;
  }

  // row sums: thread t<25 reduces heat row t, 25<=t<50 reduces layout row t-25.
  if (tid < 2 * NR) {
    const float* rowp = (tid < NR) ? &s_hrow[tid][0] : &s_lrow[tid - NR][0];
    float s = rowp[48] + rowp[49];
    const float4* r4 = reinterpret_cast<const float4*>(rowp);
    #pragma unroll
    for (int u = 0; u < 12; ++u) {
      const float4 v = r4[u];
      s += (v.x + v.y) + (v.z + v.w);
    }
    if (tid < NR) ws[WS_RS + (size_t)b * NXC + R0 + tid]        = s;
    else          ws[WS_RL + (size_t)b * NXC + R0 + (tid - NR)] = s;
  }

  // boundary-col values -> ws, coalesced
  if (tid < NR) {
    #pragma unroll
    for (int bi = 0; bi < 4; ++bi)
      ws[WS_BCOL + ((size_t)b * 4 + bi) * NXC + R0 + tid] = s_bc[bi][tid];
  }
}

// ---------------- Phase 2: closed-form Jacobi-of-sums + OHEM epilogue -------
__global__ __launch_bounds__(256, 1) void heat_phase2(
    const float* __restrict__ ws, float* __restrict__ out) {
  const int b    = blockIdx.x;
  const int tid  = threadIdx.x;
  const int wave = tid >> 6;
  const int lane = tid & 63;

  __shared__ float s_CS[NXC], s_CL[NXC], s_RS[NXC], s_RL[NXC];
  __shared__ float s_brow[4][NXC], s_bcol[4][NXC];
  __shared__ float s_red[4][4];
  __shared__ float s_sum[4];

  if (tid < NXC) {
    const float* csp = ws + WS_CSP + (size_t)b * NQ * NXC + tid;
    const float* clp = ws + WS_CLP + (size_t)b * NQ * NXC + tid;
    float a = 0.f, c = 0.f;
    #pragma unroll
    for (int qq = 0; qq < NQ; ++qq) { a += csp[qq * NXC]; c += clp[qq * NXC]; }
    s_CS[tid] = a; s_CL[tid] = c;
    s_RS[tid] = ws[WS_RS + (size_t)b * NXC + tid];
    s_RL[tid] = ws[WS_RL + (size_t)b * NXC + tid];
    #pragma unroll
    for (int bi = 0; bi < 4; ++bi) {
      s_brow[bi][tid] = ws[WS_BROW + ((size_t)b * 4 + bi) * NXC + tid];
      s_bcol[bi][tid] = ws[WS_BCOL + ((size_t)b * 4 + bi) * NXC + tid];
    }
  }
  __syncthreads();

  const float COF = (float)(0.25 * (0.1/199.0) * (0.1/199.0));
  float dv = 0.f, dh = 0.f;
  if (tid < NXC) {
    const int j  = tid;
    const int jm = (j == 0) ? 1 : j - 1;
    const int jp = (j == NXC-1) ? NXC-2 : j + 1;
    const float Sv = 0.25f * (2.f*s_CS[j]
                        + s_brow[1][j] - s_brow[3][j]     // +h[1,j] - h[199,j]
                        + s_brow[2][j] - s_brow[0][j]     // +h[198,j] - h[0,j]
                        + s_CS[jm] + s_CS[jp])
                   + COF * s_CL[j];
    dv = fabsf(Sv - s_CS[j]) * (1.f / NXC);
    const float Sh = 0.25f * (2.f*s_RS[j]
                        + s_bcol[1][j] - s_bcol[3][j]     // +h[i,1] - h[i,199]
                        + s_bcol[2][j] - s_bcol[0][j]     // +h[i,198] - h[i,0]
                        + s_RS[jm] + s_RS[jp])
                   + COF * s_RL[j];
    dh = fabsf(Sh - s_RS[j]) * (1.f / NXC);
  }

  // per-batch min/max (dv,dh >= 0 so pad 0 safe for max)
  float mnv = (tid < NXC) ? dv : INFINITY;
  float mxv = dv;
  float mnh = (tid < NXC) ? dh : INFINITY;
  float mxh = dh;
  #pragma unroll
  for (int off = 32; off > 0; off >>= 1) {
    mnv = fminf(mnv, __shfl_down(mnv, off));
    mxv = fmaxf(mxv, __shfl_down(mxv, off));
    mnh = fminf(mnh, __shfl_down(mnh, off));
    mxh = fmaxf(mxh, __shfl_down(mxh, off));
  }
  if (lane == 0) {
    s_red[0][wave] = mnv; s_red[1][wave] = mxv;
    s_red[2][wave] = mnh; s_red[3][wave] = mxh;
  }
  __syncthreads();
  const float MNV = fminf(fminf(s_red[0][0], s_red[0][1]), fminf(s_red[0][2], s_red[0][3]));
  const float MXV = fmaxf(fmaxf(s_red[1][0], s_red[1][1]), fmaxf(s_red[1][2], s_red[1][3]));
  const float MNH = fminf(fminf(s_red[2][0], s_red[2][1]), fminf(s_red[2][2], s_red[2][3]));
  const float MXH = fmaxf(fmaxf(s_red[3][0], s_red[3][1]), fmaxf(s_red[3][2], s_red[3][3]));

  float contrib = 0.f;
  if (tid < NXC) {
    contrib = 10.f * (dv - MNV) * dv / (MXV - MNV)
            + 10.f * (dh - MNH) * dh / (MXH - MNH);
  }
  #pragma unroll
  for (int off = 32; off > 0; off >>= 1) contrib += __shfl_down(contrib, off);
  if (lane == 0) s_sum[wave] = contrib;
  __syncthreads();
  if (tid == 0) {
    const float tot = (s_sum[0] + s_sum[1]) + (s_sum[2] + s_sum[3]);
    atomicAdd(out, tot * (1.f / ((float)NBB * (float)NXC)));
  }
}

extern "C" void kernel_launch(void* const* d_in, const int* in_sizes, int n_in,
                              void* d_out, int out_size, void* d_ws, size_t ws_size,
                              hipStream_t stream) {
  const float* layout = (const float*)d_in[0];
  const float* heat   = (const float*)d_in[1];
  float* out = (float*)d_out;
  float* ws  = (float*)d_ws;   // needs ~10.7 MB

  // d_out is poisoned to 0xAA before every timed launch — zero it first.
  hipMemsetAsync(out, 0, (size_t)out_size * sizeof(float), stream);
  heat_phase1<<<NBB * NQ, 256, 0, stream>>>(layout, heat, ws);
  heat_phase2<<<NBB, 256, 0, stream>>>(ws, out);
}

// Round 4
// 193.944 us; speedup vs baseline: 1.0017x; 1.0017x over previous
//
#include <hip/hip_runtime.h>
#include <math.h>

#define NXC 200   // grid edge
#define NBB 512   // batch
#define NQ  8     // row-groups per batch
#define NR  25    // rows per group
#define RST 68    // LDS row stride in floats (16B-aligned, non-pow2)

// Workspace layout (float offsets)
#define WS_CSP 0                                   // [512][8][200] heat col-sum partials
#define WS_CLP (WS_CSP + NBB*NQ*NXC)               // [512][8][200] layout col-sum partials
#define WS_RS  (WS_CLP + NBB*NQ*NXC)               // [512][200] heat row sums
#define WS_RL  (WS_RS  + NBB*NXC)                  // [512][200] layout row sums
#define WS_BROW (WS_RL + NBB*NXC)                  // [512][4][200] heat rows 0,1,198,199
#define WS_BCOL (WS_BROW + NBB*4*NXC)              // [512][4][200] heat cols 0,1,198,199

// ---------------- Phase 1: streaming scan, preload-then-accumulate ----------
// Block g: batch b = g/8, row-group q = g%8 (rows 25q .. 25q+24).
// Wave w owns local rows rl = w + 4k, k=0..6 (ragged: clamped wave-uniformly).
// ALL 14 float4 loads (7 rows x {heat,layout}) are issued unconditionally and
// back-to-back into register buffers (lanes >=50 clamp to lane 49's address;
// ragged rows clamp to row R0) so the wave has ~11 KB in flight, then the
// accumulate phase consumes them under fine-grained vmcnt waits.
__global__ __launch_bounds__(256, 1) void heat_phase1(
    const float* __restrict__ layout, const float* __restrict__ heat,
    float* __restrict__ ws) {
  const int g    = blockIdx.x;
  const int b    = g >> 3;
  const int q    = g & 7;
  const int R0   = NR * q;
  const int tid  = threadIdx.x;
  const int wave = tid >> 6;
  const int lane = tid & 63;

  __shared__ __align__(16) float s_hrow[NR][RST];
  __shared__ __align__(16) float s_lrow[NR][RST];
  __shared__ float s_hcol[4][NXC];
  __shared__ float s_lcol[4][NXC];
  __shared__ float s_bc[4][NR];    // boundary-col values for owned rows

  const float4* __restrict__ hp =
      reinterpret_cast<const float4*>(heat + (size_t)b * NXC * NXC);
  const float4* __restrict__ lp =
      reinterpret_cast<const float4*>(layout + (size_t)b * NXC * NXC);

  const int li = (lane < 50) ? lane : 49;   // clamp: no exec-masked loads

  // ---- issue all 14 loads up front (no waits between them) ----
  float4 hbuf[7], lbuf[7];
  #pragma unroll
  for (int k = 0; k < 7; ++k) {
    const int rl  = wave + 4 * k;                 // wave-uniform
    const int row = R0 + ((rl < NR) ? rl : 0);    // wave-uniform clamp
    hbuf[k] = hp[row * 50 + li];
    lbuf[k] = lp[row * 50 + li];
  }

  // ---- consume ----
  float hc0=0.f,hc1=0.f,hc2=0.f,hc3=0.f;
  float lc0=0.f,lc1=0.f,lc2=0.f,lc3=0.f;
  const bool act = (lane < 50);

  #pragma unroll
  for (int k = 0; k < 7; ++k) {
    const int rl = wave + 4 * k;
    if (rl < NR) {                                // wave-uniform branch
      const int i = R0 + rl;                      // global row
      const float4 hv = hbuf[k];
      const float4 lv = lbuf[k];
      // lanes >=50 hold duplicates of lane 49; their accumulators are
      // never read (col-partial stores below are guarded by `act`).
      hc0 += hv.x; hc1 += hv.y; hc2 += hv.z; hc3 += hv.w;
      lc0 += lv.x; lc1 += lv.y; lc2 += lv.z; lc3 += lv.w;
      if (act) {
        s_hrow[rl][lane] = (hv.x + hv.y) + (hv.z + hv.w);
        s_lrow[rl][lane] = (lv.x + lv.y) + (lv.z + lv.w);
        // boundary rows of heat (i in {0,1,198,199}) -> ws, coalesced float4
        if (i <= 1 || i >= NXC - 2) {
          const int bi = (i <= 1) ? i : i - (NXC - 4);
          float4* dst = reinterpret_cast<float4*>(
              ws + WS_BROW + ((size_t)b * 4 + bi) * NXC);
          dst[lane] = hv;
        }
        // boundary cols of heat: j=0,1 from lane 0; j=198,199 from lane 49
        if (lane == 0)  { s_bc[0][rl] = hv.x; s_bc[1][rl] = hv.y; }
        if (lane == 49) { s_bc[2][rl] = hv.z; s_bc[3][rl] = hv.w; }
      }
    }
  }

  if (act) {
    s_hcol[wave][4*lane+0] = hc0; s_hcol[wave][4*lane+1] = hc1;
    s_hcol[wave][4*lane+2] = hc2; s_hcol[wave][4*lane+3] = hc3;
    s_lcol[wave][4*lane+0] = lc0; s_lcol[wave][4*lane+1] = lc1;
    s_lcol[wave][4*lane+2] = lc2; s_lcol[wave][4*lane+3] = lc3;
  }
  __syncthreads();

  // column-sum partials for this row-group -> ws (disjoint slots, no atomics)
  if (tid < NXC) {
    const float a = (s_hcol[0][tid] + s_hcol[1][tid]) + (s_hcol[2][tid] + s_hcol[3][tid]);
    const float c = (s_lcol[0][tid] + s_lcol[1][tid]) + (s_lcol[2][tid] + s_lcol[3][tid]);
    ws[WS_CSP + ((size_t)b * NQ + q) * NXC + tid] = a;
    ws[WS_CLP + ((size_t)b * NQ + q) * NXC + tid] = c;
  }

  // row sums: thread t<25 reduces heat row t, 25<=t<50 reduces layout row t-25.
  if (tid < 2 * NR) {
    const float* rowp = (tid < NR) ? &s_hrow[tid][0] : &s_lrow[tid - NR][0];
    float s = rowp[48] + rowp[49];
    const float4* r4 = reinterpret_cast<const float4*>(rowp);
    #pragma unroll
    for (int u = 0; u < 12; ++u) {
      const float4 v = r4[u];
      s += (v.x + v.y) + (v.z + v.w);
    }
    if (tid < NR) ws[WS_RS + (size_t)b * NXC + R0 + tid]        = s;
    else          ws[WS_RL + (size_t)b * NXC + R0 + (tid - NR)] = s;
  }

  // boundary-col values -> ws, coalesced
  if (tid < NR) {
    #pragma unroll
    for (int bi = 0; bi < 4; ++bi)
      ws[WS_BCOL + ((size_t)b * 4 + bi) * NXC + R0 + tid] = s_bc[bi][tid];
  }
}

// ---------------- Phase 2: closed-form Jacobi-of-sums + OHEM epilogue -------
__global__ __launch_bounds__(256, 1) void heat_phase2(
    const float* __restrict__ ws, float* __restrict__ out) {
  const int b    = blockIdx.x;
  const int tid  = threadIdx.x;
  const int wave = tid >> 6;
  const int lane = tid & 63;

  __shared__ float s_CS[NXC], s_CL[NXC], s_RS[NXC], s_RL[NXC];
  __shared__ float s_brow[4][NXC], s_bcol[4][NXC];
  __shared__ float s_red[4][4];
  __shared__ float s_sum[4];

  if (tid < NXC) {
    const float* csp = ws + WS_CSP + (size_t)b * NQ * NXC + tid;
    const float* clp = ws + WS_CLP + (size_t)b * NQ * NXC + tid;
    float a = 0.f, c = 0.f;
    #pragma unroll
    for (int qq = 0; qq < NQ; ++qq) { a += csp[qq * NXC]; c += clp[qq * NXC]; }
    s_CS[tid] = a; s_CL[tid] = c;
    s_RS[tid] = ws[WS_RS + (size_t)b * NXC + tid];
    s_RL[tid] = ws[WS_RL + (size_t)b * NXC + tid];
    #pragma unroll
    for (int bi = 0; bi < 4; ++bi) {
      s_brow[bi][tid] = ws[WS_BROW + ((size_t)b * 4 + bi) * NXC + tid];
      s_bcol[bi][tid] = ws[WS_BCOL + ((size_t)b * 4 + bi) * NXC + tid];
    }
  }
  __syncthreads();

  const float COF = (float)(0.25 * (0.1/199.0) * (0.1/199.0));
  float dv = 0.f, dh = 0.f;
  if (tid < NXC) {
    const int j  = tid;
    const int jm = (j == 0) ? 1 : j - 1;
    const int jp = (j == NXC-1) ? NXC-2 : j + 1;
    const float Sv = 0.25f * (2.f*s_CS[j]
                        + s_brow[1][j] - s_brow[3][j]     // +h[1,j] - h[199,j]
                        + s_brow[2][j] - s_brow[0][j]     // +h[198,j] - h[0,j]
                        + s_CS[jm] + s_CS[jp])
                   + COF * s_CL[j];
    dv = fabsf(Sv - s_CS[j]) * (1.f / NXC);
    const float Sh = 0.25f * (2.f*s_RS[j]
                        + s_bcol[1][j] - s_bcol[3][j]     // +h[i,1] - h[i,199]
                        + s_bcol[2][j] - s_bcol[0][j]     // +h[i,198] - h[i,0]
                        + s_RS[jm] + s_RS[jp])
                   + COF * s_RL[j];
    dh = fabsf(Sh - s_RS[j]) * (1.f / NXC);
  }

  // per-batch min/max (dv,dh >= 0 so pad 0 safe for max)
  float mnv = (tid < NXC) ? dv : INFINITY;
  float mxv = dv;
  float mnh = (tid < NXC) ? dh : INFINITY;
  float mxh = dh;
  #pragma unroll
  for (int off = 32; off > 0; off >>= 1) {
    mnv = fminf(mnv, __shfl_down(mnv, off));
    mxv = fmaxf(mxv, __shfl_down(mxv, off));
    mnh = fminf(mnh, __shfl_down(mnh, off));
    mxh = fmaxf(mxh, __shfl_down(mxh, off));
  }
  if (lane == 0) {
    s_red[0][wave] = mnv; s_red[1][wave] = mxv;
    s_red[2][wave] = mnh; s_red[3][wave] = mxh;
  }
  __syncthreads();
  const float MNV = fminf(fminf(s_red[0][0], s_red[0][1]), fminf(s_red[0][2], s_red[0][3]));
  const float MXV = fmaxf(fmaxf(s_red[1][0], s_red[1][1]), fmaxf(s_red[1][2], s_red[1][3]));
  const float MNH = fminf(fminf(s_red[2][0], s_red[2][1]), fminf(s_red[2][2], s_red[2][3]));
  const float MXH = fmaxf(fmaxf(s_red[3][0], s_red[3][1]), fmaxf(s_red[3][2], s_red[3][3]));

  float contrib = 0.f;
  if (tid < NXC) {
    contrib = 10.f * (dv - MNV) * dv / (MXV - MNV)
            + 10.f * (dh - MNH) * dh / (MXH - MNH);
  }
  #pragma unroll
  for (int off = 32; off > 0; off >>= 1) contrib += __shfl_down(contrib, off);
  if (lane == 0) s_sum[wave] = contrib;
  __syncthreads();
  if (tid == 0) {
    const float tot = (s_sum[0] + s_sum[1]) + (s_sum[2] + s_sum[3]);
    atomicAdd(out, tot * (1.f / ((float)NBB * (float)NXC)));
  }
}

extern "C" void kernel_launch(void* const* d_in, const int* in_sizes, int n_in,
                              void* d_out, int out_size, void* d_ws, size_t ws_size,
                              hipStream_t stream) {
  const float* layout = (const float*)d_in[0];
  const float* heat   = (const float*)d_in[1];
  float* out = (float*)d_out;
  float* ws  = (float*)d_ws;   // needs ~10.7 MB

  // d_out is poisoned to 0xAA before every timed launch — zero it first.
  hipMemsetAsync(out, 0, (size_t)out_size * sizeof(float), stream);
  heat_phase1<<<NBB * NQ, 256, 0, stream>>>(layout, heat, ws);
  heat_phase2<<<NBB, 256, 0, stream>>>(ws, out);
}

// Round 5
// 192.998 us; speedup vs baseline: 1.0066x; 1.0049x over previous
//
#include <hip/hip_runtime.h>
#include <math.h>

#define NXC 200     // grid edge
#define NBB 512     // batch
#define CHROWS 64   // rows per chunk (64*200*4 B = 51200 B = 50 x 1024 B DMA)
#define CHFLT (CHROWS * NXC)          // 12800 floats per chunk
#define NCHUNK (NBB * NXC / CHROWS)   // 1600 chunks per array

// Workspace layout (float offsets). Col bins are atomic-accumulated -> must be
// zeroed before each launch (done via hipMemsetAsync in kernel_launch).
#define WS_CS   0                          // [512][200] heat col sums (atomic)
#define WS_CL   (WS_CS + NBB * NXC)        // [512][200] layout col sums (atomic)
#define WS_RS   (WS_CL + NBB * NXC)        // [512*200]  heat row sums
#define WS_RL   (WS_RS + NBB * NXC)        // [512*200]  layout row sums
#define WS_BROW (WS_RL + NBB * NXC)        // [512][4][200] heat rows 0,1,198,199
#define WS_BCOL (WS_BROW + NBB * 4 * NXC)  // [512][4][200] heat cols 0,1,198,199

// ---------------- Phase 1: DMA-staged full-density streaming ----------------
// Block g < 1600: heat chunk g. Block g >= 1600: layout chunk g-1600.
// Chunk = 64 consecutive global rows (batch-straddling handled via 2 col bins).
__global__ __launch_bounds__(512, 1) void heat_stage(
    const float* __restrict__ layout, const float* __restrict__ heat,
    float* __restrict__ ws) {
  const int g      = blockIdx.x;
  const bool isHeat = (g < NCHUNK);
  const int chunk  = isHeat ? g : g - NCHUNK;
  const float* __restrict__ src =
      (isHeat ? heat : layout) + (size_t)chunk * CHFLT;

  __shared__ __align__(16) float stage[CHFLT];   // 51200 B
  __shared__ float s_cA[2][2][NXC];              // [grp][bin] col partials
  __shared__ float s_rp[CHROWS][8];              // row partials

  const int tid  = threadIdx.x;
  const int wave = tid >> 6;
  const int lane = tid & 63;

  // ---- stage: 50 x 1024-B global_load_lds, 100% dense, no VGPR results ----
  for (int c = wave; c < 50; c += 8) {
    const float* gp = src + c * 256 + lane * 4;        // per-lane global addr
    __builtin_amdgcn_global_load_lds(
        (const __attribute__((address_space(1))) void*)gp,
        (__attribute__((address_space(3))) void*)&stage[c * 256],  // +lane*16
        16, 0, 0);
  }
  __syncthreads();   // compiler emits vmcnt(0) drain before barrier

  const int R0      = chunk * CHROWS;        // first global row of chunk
  const int b0      = R0 / NXC;              // first batch touched
  int rows_b0 = (b0 + 1) * NXC - R0;         // rows belonging to batch b0
  if (rows_b0 > CHROWS) rows_b0 = CHROWS;

  // ---- pass A: column partials (2 row-halves in parallel) ----
  const int grp = tid >> 8;     // 0: rows 0..31, 1: rows 32..63
  const int t2  = tid & 255;
  if (t2 < NXC) {
    float a0 = 0.f, a1 = 0.f;
    const int rb = 32 * grp;
    #pragma unroll
    for (int r = 0; r < 32; ++r) {
      const float x = stage[(rb + r) * NXC + t2];
      if (rb + r < rows_b0) a0 += x; else a1 += x;   // uniform branch
    }
    s_cA[grp][0][t2] = a0;
    s_cA[grp][1][t2] = a1;
  }

  // ---- pass B: row partials, 8 threads x 25 floats per row (2-way banks) ---
  {
    const int r = tid >> 3, k = tid & 7;
    const float* rp = &stage[r * NXC + k * 25];
    float s = 0.f;
    #pragma unroll
    for (int j = 0; j < 25; ++j) s += rp[j];
    s_rp[r][k] = s;
  }
  __syncthreads();

  // col bins -> global atomic (<=6 adders per address over whole grid)
  if (tid < NXC) {
    const float a0 = s_cA[0][0][tid] + s_cA[1][0][tid];
    const float a1 = s_cA[0][1][tid] + s_cA[1][1][tid];
    float* colbase = ws + (isHeat ? WS_CS : WS_CL);
    atomicAdd(colbase + b0 * NXC + tid, a0);
    if (rows_b0 < CHROWS) atomicAdd(colbase + (b0 + 1) * NXC + tid, a1);
  }

  // row sums -> direct store; heat boundary cols j in {0,1,198,199}
  if (tid < CHROWS) {
    float s = 0.f;
    #pragma unroll
    for (int k = 0; k < 8; ++k) s += s_rp[tid][k];
    const int R = R0 + tid;
    ws[(isHeat ? WS_RS : WS_RL) + R] = s;
    if (isHeat) {
      const int b = R / NXC, i = R % NXC;
      ws[WS_BCOL + ((size_t)b * 4 + 0) * NXC + i] = stage[tid * NXC + 0];
      ws[WS_BCOL + ((size_t)b * 4 + 1) * NXC + i] = stage[tid * NXC + 1];
      ws[WS_BCOL + ((size_t)b * 4 + 2) * NXC + i] = stage[tid * NXC + NXC - 2];
      ws[WS_BCOL + ((size_t)b * 4 + 3) * NXC + i] = stage[tid * NXC + NXC - 1];
    }
  }

  // heat boundary rows i in {0,1,198,199}: <=4 per chunk, uniform branch scan
  if (isHeat && tid < NXC) {
    for (int r = 0; r < CHROWS; ++r) {
      const int R = R0 + r, i = R % NXC;
      const int bi = (i == 0) ? 0 : (i == 1) ? 1
                   : (i == NXC - 2) ? 2 : (i == NXC - 1) ? 3 : -1;
      if (bi >= 0)
        ws[WS_BROW + ((size_t)(R / NXC) * 4 + bi) * NXC + tid] =
            stage[r * NXC + tid];
    }
  }
}

// ---------------- Phase 2: closed-form Jacobi-of-sums + OHEM epilogue -------
__global__ __launch_bounds__(256, 1) void heat_phase2(
    const float* __restrict__ ws, float* __restrict__ out) {
  const int b    = blockIdx.x;
  const int tid  = threadIdx.x;
  const int wave = tid >> 6;
  const int lane = tid & 63;

  __shared__ float s_CS[NXC], s_CL[NXC], s_RS[NXC], s_RL[NXC];
  __shared__ float s_brow[4][NXC], s_bcol[4][NXC];
  __shared__ float s_red[4][4];
  __shared__ float s_sum[4];

  if (tid < NXC) {
    s_CS[tid] = ws[WS_CS + (size_t)b * NXC + tid];
    s_CL[tid] = ws[WS_CL + (size_t)b * NXC + tid];
    s_RS[tid] = ws[WS_RS + (size_t)b * NXC + tid];
    s_RL[tid] = ws[WS_RL + (size_t)b * NXC + tid];
    #pragma unroll
    for (int bi = 0; bi < 4; ++bi) {
      s_brow[bi][tid] = ws[WS_BROW + ((size_t)b * 4 + bi) * NXC + tid];
      s_bcol[bi][tid] = ws[WS_BCOL + ((size_t)b * 4 + bi) * NXC + tid];
    }
  }
  __syncthreads();

  const float COF = (float)(0.25 * (0.1/199.0) * (0.1/199.0));
  float dv = 0.f, dh = 0.f;
  if (tid < NXC) {
    const int j  = tid;
    const int jm = (j == 0) ? 1 : j - 1;
    const int jp = (j == NXC-1) ? NXC-2 : j + 1;
    const float Sv = 0.25f * (2.f*s_CS[j]
                        + s_brow[1][j] - s_brow[3][j]     // +h[1,j] - h[199,j]
                        + s_brow[2][j] - s_brow[0][j]     // +h[198,j] - h[0,j]
                        + s_CS[jm] + s_CS[jp])
                   + COF * s_CL[j];
    dv = fabsf(Sv - s_CS[j]) * (1.f / NXC);
    const float Sh = 0.25f * (2.f*s_RS[j]
                        + s_bcol[1][j] - s_bcol[3][j]     // +h[i,1] - h[i,199]
                        + s_bcol[2][j] - s_bcol[0][j]     // +h[i,198] - h[i,0]
                        + s_RS[jm] + s_RS[jp])
                   + COF * s_RL[j];
    dh = fabsf(Sh - s_RS[j]) * (1.f / NXC);
  }

  float mnv = (tid < NXC) ? dv : INFINITY;
  float mxv = dv;
  float mnh = (tid < NXC) ? dh : INFINITY;
  float mxh = dh;
  #pragma unroll
  for (int off = 32; off > 0; off >>= 1) {
    mnv = fminf(mnv, __shfl_down(mnv, off));
    mxv = fmaxf(mxv, __shfl_down(mxv, off));
    mnh = fminf(mnh, __shfl_down(mnh, off));
    mxh = fmaxf(mxh, __shfl_down(mxh, off));
  }
  if (lane == 0) {
    s_red[0][wave] = mnv; s_red[1][wave] = mxv;
    s_red[2][wave] = mnh; s_red[3][wave] = mxh;
  }
  __syncthreads();
  const float MNV = fminf(fminf(s_red[0][0], s_red[0][1]), fminf(s_red[0][2], s_red[0][3]));
  const float MXV = fmaxf(fmaxf(s_red[1][0], s_red[1][1]), fmaxf(s_red[1][2], s_red[1][3]));
  const float MNH = fminf(fminf(s_red[2][0], s_red[2][1]), fminf(s_red[2][2], s_red[2][3]));
  const float MXH = fmaxf(fmaxf(s_red[3][0], s_red[3][1]), fmaxf(s_red[3][2], s_red[3][3]));

  float contrib = 0.f;
  if (tid < NXC) {
    contrib = 10.f * (dv - MNV) * dv / (MXV - MNV)
            + 10.f * (dh - MNH) * dh / (MXH - MNH);
  }
  #pragma unroll
  for (int off = 32; off > 0; off >>= 1) contrib += __shfl_down(contrib, off);
  if (lane == 0) s_sum[wave] = contrib;
  __syncthreads();
  if (tid == 0) {
    const float tot = (s_sum[0] + s_sum[1]) + (s_sum[2] + s_sum[3]);
    atomicAdd(out, tot * (1.f / ((float)NBB * (float)NXC)));
  }
}

extern "C" void kernel_launch(void* const* d_in, const int* in_sizes, int n_in,
                              void* d_out, int out_size, void* d_ws, size_t ws_size,
                              hipStream_t stream) {
  const float* layout = (const float*)d_in[0];
  const float* heat   = (const float*)d_in[1];
  float* out = (float*)d_out;
  float* ws  = (float*)d_ws;   // needs ~4.9 MB

  // d_out / d_ws are poisoned to 0xAA before every timed launch.
  hipMemsetAsync(out, 0, (size_t)out_size * sizeof(float), stream);
  // zero the atomic col-sum bins (2 x 512 x 200 floats)
  hipMemsetAsync(ws, 0, (size_t)2 * NBB * NXC * sizeof(float), stream);
  heat_stage<<<2 * NCHUNK, 512, 0, stream>>>(layout, heat, ws);
  heat_phase2<<<NBB, 256, 0, stream>>>(ws, out);
}